// Round 2
// baseline (675.217 us; speedup 1.0000x reference)
//
#include <hip/hip_runtime.h>

#define SEQ   512
#define BATCH 256
#define INDIM 784
#define HID   10
#define NC4   196   // INDIM / 4
#define CHUNK 56    // columns staged per iteration (784 = 14 * 56)
#define NCH   14
#define STR   257   // LDS row stride in floats (odd -> <=2-way bank aliasing)
#define PF    8     // scan prefetch depth (steps)
#define SEG   256   // timesteps per scan segment (= producer phase size)

typedef float f4 __attribute__((ext_vector_type(4)));

// ---------------------------------------------------------------------------
// Producer: xi[t*B+b][j] = x[t,b,:] . W_ih[j] + b_ih[j] + b_hh[j].
// One block = one timestep (256 rows, lane-per-row). x staged through LDS
// TRANSPOSED in CHUNK-column slabs: compute read lds[c*STR+tid] is stride-1
// across lanes (conflict-free); write (4c+k)*STR+r with odd STR is <=2-way
// (free). W read with wave-uniform indices -> scalar SMEM loads. Next chunk
// prefetched into registers. x loads nontemporal (411 MB streamed once).
// ---------------------------------------------------------------------------
__device__ __forceinline__ void produce_t(
    const float* __restrict__ x, const float* __restrict__ Wih,
    const float* __restrict__ bih, const float* __restrict__ bhh,
    float* __restrict__ xi, float* lds, int t)
{
    const int tid  = threadIdx.x;
    const long row0 = (long)t * 256;
    const f4* x4 = (const f4*)x + row0 * NC4;

    float acc[HID];
#pragma unroll
    for (int j = 0; j < HID; ++j) acc[j] = bih[j] + bhh[j];

    f4 stg[14];
#pragma unroll
    for (int k = 0; k < 14; ++k) {
        const int idx = k * 256 + tid;
        const int c4 = idx % 14, r = idx / 14;
        stg[k] = __builtin_nontemporal_load(&x4[(long)r * NC4 + c4]);
    }

    for (int ch = 0; ch < NCH; ++ch) {
#pragma unroll
        for (int k = 0; k < 14; ++k) {
            const int idx = k * 256 + tid;
            const int c4 = idx % 14, r = idx / 14;
            const int cb = c4 * 4;
            lds[(cb + 0) * STR + r] = stg[k][0];
            lds[(cb + 1) * STR + r] = stg[k][1];
            lds[(cb + 2) * STR + r] = stg[k][2];
            lds[(cb + 3) * STR + r] = stg[k][3];
        }
        __syncthreads();

        if (ch + 1 < NCH) {
#pragma unroll
            for (int k = 0; k < 14; ++k) {
                const int idx = k * 256 + tid;
                const int c4 = idx % 14, r = idx / 14;
                stg[k] = __builtin_nontemporal_load(
                    &x4[(long)r * NC4 + (ch + 1) * 14 + c4]);
            }
        }

        const float* wch = Wih + ch * CHUNK;
#pragma unroll 4
        for (int c = 0; c < CHUNK; ++c) {
            const float xv = lds[c * STR + tid];
#pragma unroll
            for (int j = 0; j < HID; ++j)
                acc[j] = fmaf(xv, wch[j * INDIM + c], acc[j]);
        }
        __syncthreads();
    }

    float* po = xi + (row0 + tid) * HID;
#pragma unroll
    for (int j = 0; j < HID; ++j) po[j] = acc[j];
}

// ---------------------------------------------------------------------------
// Scan segment: h_t = relu(xi_t + h_{t-1} @ W_hh^T) for t in [S0, S0+SEG).
// 2 threads per batch element (xor-1 pair in-wave), 5 hidden dims each; W
// columns permuted per thread so no runtime register indexing. 8-deep
// register ring prefetch of xi (static indexing: t-loop unrolled by PF),
// tail peeled so the ring never reads past S0+SEG-1 (the produced frontier).
// h state is parked in / restored from hstate across segments (launches).
// ---------------------------------------------------------------------------
template <int S0>
__device__ __forceinline__ void scan_seg(
    const float* __restrict__ xi, const float* __restrict__ Whh,
    float* __restrict__ out, float* __restrict__ hstate, int gid)
{
    const int b    = gid >> 1;
    const int half = gid & 1;
    const int j0   = half * 5;

    // W[jj][k]: row j0+jj, columns permuted: k<5 -> dim k+j0, k>=5 -> k-j0
    float W[5][10];
#pragma unroll
    for (int jj = 0; jj < 5; ++jj)
#pragma unroll
        for (int k = 0; k < 10; ++k) {
            const int col = (k < 5) ? (k + j0) : (k - j0);
            W[jj][k] = Whh[(j0 + jj) * HID + col];
        }

    float h[10];
    if (S0 == 0) {
#pragma unroll
        for (int k = 0; k < 10; ++k) h[k] = 0.f;
    } else {
        const float* hs = hstate + b * HID;
#pragma unroll
        for (int jj = 0; jj < 5; ++jj) {
            h[jj]     = hs[j0 + jj];
            h[5 + jj] = hs[(5 - j0) + jj];
        }
    }

    const float* xib  = xi  + b * HID + j0;
    float*       outb = out + b * HID + j0;

    // fill the ring: steps S0..S0+PF-1
    float buf[PF][5];
#pragma unroll
    for (int i = 0; i < PF; ++i) {
        const float* p = xib + (long)(S0 + i) * (BATCH * HID);
#pragma unroll
        for (int jj = 0; jj < 5; ++jj) buf[i][jj] = p[jj];
    }

    for (int t0 = S0; t0 < S0 + SEG - PF; t0 += PF) {
#pragma unroll
        for (int i = 0; i < PF; ++i) {
            const int t = t0 + i;

            float cur[5];
#pragma unroll
            for (int jj = 0; jj < 5; ++jj) cur[jj] = buf[i][jj];

            // issue prefetch for t+PF immediately (full PF-step window);
            // t+PF <= S0+SEG-1: never crosses the produced frontier
            const float* p = xib + (long)(t + PF) * (BATCH * HID);
#pragma unroll
            for (int jj = 0; jj < 5; ++jj) buf[i][jj] = p[jj];

            float s[5];
#pragma unroll
            for (int jj = 0; jj < 5; ++jj) {
                float a0 = cur[jj];
                float a1 = W[jj][5] * h[5];
#pragma unroll
                for (int k = 0; k < 5; ++k) a0 = fmaf(W[jj][k], h[k], a0);
#pragma unroll
                for (int k = 6; k < 10; ++k) a1 = fmaf(W[jj][k], h[k], a1);
                s[jj] = fmaxf(a0 + a1, 0.f);
            }

            float* po = outb + (long)t * (BATCH * HID);
#pragma unroll
            for (int jj = 0; jj < 5; ++jj) po[jj] = s[jj];

#pragma unroll
            for (int jj = 0; jj < 5; ++jj) {
                h[jj]     = s[jj];
                h[5 + jj] = __shfl_xor(s[jj], 1, 64);
            }
        }
    }

    // tail: last PF steps of the segment, ring already holds them
#pragma unroll
    for (int i = 0; i < PF; ++i) {
        const int t = S0 + SEG - PF + i;

        float s[5];
#pragma unroll
        for (int jj = 0; jj < 5; ++jj) {
            float a0 = buf[i][jj];
            float a1 = W[jj][5] * h[5];
#pragma unroll
            for (int k = 0; k < 5; ++k) a0 = fmaf(W[jj][k], h[k], a0);
#pragma unroll
            for (int k = 6; k < 10; ++k) a1 = fmaf(W[jj][k], h[k], a1);
            s[jj] = fmaxf(a0 + a1, 0.f);
        }

        float* po = outb + (long)t * (BATCH * HID);
#pragma unroll
        for (int jj = 0; jj < 5; ++jj) po[jj] = s[jj];

#pragma unroll
        for (int jj = 0; jj < 5; ++jj) {
            h[jj]     = s[jj];
            h[5 + jj] = __shfl_xor(s[jj], 1, 64);
        }
    }

    if (S0 == 0) {
        // park h for the next segment (next launch)
        float* hs = hstate + b * HID;
#pragma unroll
        for (int jj = 0; jj < 5; ++jj) hs[j0 + jj] = h[jj];
    } else {
        // final h_n
        float* pl = out + (long)SEQ * BATCH * HID + b * HID + j0;
#pragma unroll
        for (int jj = 0; jj < 5; ++jj) pl[jj] = h[jj];
    }
}

// ---------------------------------------------------------------------------
// L1: produce xi for t = 0..255. 256 blocks (1/CU), HBM-bound.
// ---------------------------------------------------------------------------
__global__ __launch_bounds__(256) void produce0_kernel(
    const float* __restrict__ x, const float* __restrict__ Wih,
    const float* __restrict__ bih, const float* __restrict__ bhh,
    float* __restrict__ xi)
{
    __shared__ float lds[CHUNK * STR];
    produce_t(x, Wih, bih, bhh, xi, lds, blockIdx.x);
}

// ---------------------------------------------------------------------------
// L2: blocks 0..1 scan t = 0..255 (xi complete from L1, coherence via the
// kernel boundary); blocks 2..257 produce xi for t = 256..511. Scan (~21us)
// hides under production (~36us). 258 blocks, all resident.
// ---------------------------------------------------------------------------
__global__ __launch_bounds__(256) void mixed_kernel(
    const float* __restrict__ x, const float* __restrict__ Wih,
    const float* __restrict__ bih, const float* __restrict__ bhh,
    float* __restrict__ xi, const float* __restrict__ Whh,
    float* __restrict__ out, float* __restrict__ hstate)
{
    __shared__ float lds[CHUNK * STR];
    if (blockIdx.x < 2) {
        scan_seg<0>(xi, Whh, out, hstate, blockIdx.x * 256 + threadIdx.x);
    } else {
        produce_t(x, Wih, bih, bhh, xi, lds, 256 + (int)blockIdx.x - 2);
    }
}

// ---------------------------------------------------------------------------
// L3: scan t = 256..511 (xi complete from L2), restore h, write h_n.
// ---------------------------------------------------------------------------
__global__ __launch_bounds__(256) void scan1_kernel(
    const float* __restrict__ xi, const float* __restrict__ Whh,
    float* __restrict__ out, float* __restrict__ hstate)
{
    scan_seg<SEG>(xi, Whh, out, hstate, blockIdx.x * 256 + threadIdx.x);
}

// ---------------------------------------------------------------------------
extern "C" void kernel_launch(void* const* d_in, const int* in_sizes, int n_in,
                              void* d_out, int out_size, void* d_ws, size_t ws_size,
                              hipStream_t stream)
{
    const float* x   = (const float*)d_in[0];
    const float* Wih = (const float*)d_in[1];
    const float* Whh = (const float*)d_in[2];
    const float* bih = (const float*)d_in[3];
    const float* bhh = (const float*)d_in[4];
    float* out = (float*)d_out;
    float* xi  = (float*)d_ws;                       // SEQ*BATCH*HID = 5.24 MB
    float* hstate = xi + (long)SEQ * BATCH * HID;    // 2560 floats

    produce0_kernel<<<256, 256, 0, stream>>>(x, Wih, bih, bhh, xi);
    mixed_kernel<<<258, 256, 0, stream>>>(x, Wih, bih, bhh, xi, Whh, out, hstate);
    scan1_kernel<<<2, 256, 0, stream>>>(xi, Whh, out, hstate);
}

// Round 3
// 627.298 us; speedup vs baseline: 1.0764x; 1.0764x over previous
//
#include <hip/hip_runtime.h>

#define SEQ   512
#define BATCH 256
#define INDIM 784
#define HID   10
#define NC4   196   // INDIM / 4
#define CHUNK 56    // columns staged per iteration (784 = 14 * 56)
#define NCH   14
#define STR   257   // LDS row stride in floats (odd -> <=2-way bank aliasing)
#define PF    16    // scan prefetch depth (steps); 2 load instrs/step -> 32 in flight
#define XIP   16    // padded xi row stride (floats): each half's 5 floats 32B-aligned

typedef float f4 __attribute__((ext_vector_type(4)));
typedef float f2 __attribute__((ext_vector_type(2)));

static __device__ __forceinline__ f2 mk2(float a, float b) {
    f2 r; r[0] = a; r[1] = b; return r;
}

// ---------------------------------------------------------------------------
// Kernel 1: xi[row][j] = x[row] . W_ih[j] + b_ih[j] + b_hh[j],  row = t*B+b.
// Lane-per-row, 512 blocks (2/CU). x staged through LDS TRANSPOSED in
// CHUNK-column slabs: compute read lds[c*STR+tid] is stride-1 across lanes
// (conflict-free); write (4c+k)*STR+r with odd STR is <=2-way (free). W read
// wave-uniform -> scalar SMEM loads. Next chunk prefetched into registers.
// PLAIN loads for x (no nontemporal): the 224B-per-14-lane segments straddle
// 128B lines (row stride 3136B = 24.5 lines); the boundary halves belong to
// the NEXT chunk's columns, so L2 must be allowed to cache them.
// xi stored PADDED to 16 floats/row: dims 0-4 at [0..4], dims 5-9 at [8..12]
// so the scan reads each half as one aligned dwordx4 + dword.
// ---------------------------------------------------------------------------
__global__ __launch_bounds__(256) void xproj_kernel(
    const float* __restrict__ x, const float* __restrict__ Wih,
    const float* __restrict__ bih, const float* __restrict__ bhh,
    float* __restrict__ xi)
{
    __shared__ float lds[CHUNK * STR];   // 57,568 B -> 2 blocks/CU

    const int tid  = threadIdx.x;
    const long row0 = (long)blockIdx.x * 256;
    const f4* x4 = (const f4*)x + row0 * NC4;

    float acc[HID];
#pragma unroll
    for (int j = 0; j < HID; ++j) acc[j] = bih[j] + bhh[j];

    f4 stg[14];
    // preload chunk 0: 256 rows x 14 float4 (c4 fastest within 14-lane groups)
#pragma unroll
    for (int k = 0; k < 14; ++k) {
        const int idx = k * 256 + tid;
        const int c4 = idx % 14, r = idx / 14;
        stg[k] = x4[(long)r * NC4 + c4];
    }

    for (int ch = 0; ch < NCH; ++ch) {
        // staged regs -> LDS, transposed
#pragma unroll
        for (int k = 0; k < 14; ++k) {
            const int idx = k * 256 + tid;
            const int c4 = idx % 14, r = idx / 14;
            const int cb = c4 * 4;
            lds[(cb + 0) * STR + r] = stg[k][0];
            lds[(cb + 1) * STR + r] = stg[k][1];
            lds[(cb + 2) * STR + r] = stg[k][2];
            lds[(cb + 3) * STR + r] = stg[k][3];
        }
        __syncthreads();

        // prefetch next chunk while computing this one
        if (ch + 1 < NCH) {
#pragma unroll
            for (int k = 0; k < 14; ++k) {
                const int idx = k * 256 + tid;
                const int c4 = idx % 14, r = idx / 14;
                stg[k] = x4[(long)r * NC4 + (ch + 1) * 14 + c4];
            }
        }

        const float* wch = Wih + ch * CHUNK;
#pragma unroll 4
        for (int c = 0; c < CHUNK; ++c) {
            const float xv = lds[c * STR + tid];
#pragma unroll
            for (int j = 0; j < HID; ++j)
                acc[j] = fmaf(xv, wch[j * INDIM + c], acc[j]);
        }
        __syncthreads();
    }

    // padded store: [0..3],[4] and [8..11],[12]; rows 64B apart -> coalesced
    float* po = xi + (row0 + tid) * XIP;
    f4 lo; lo[0] = acc[0]; lo[1] = acc[1]; lo[2] = acc[2]; lo[3] = acc[3];
    f4 hi; hi[0] = acc[5]; hi[1] = acc[6]; hi[2] = acc[7]; hi[3] = acc[8];
    *(f4*)po = lo;        po[4]  = acc[4];
    *(f4*)(po + 8) = hi;  po[12] = acc[9];
}

// ---------------------------------------------------------------------------
// Kernel 2: h_t = relu(xi_t + h_{t-1} @ W_hh^T). 2 threads per batch element
// (xor-1 pair in-wave), 5 hidden dims each; W columns permuted per thread so
// h-indexing is static (own dims in h[0..4], partner's in h[5..9]).
//
// NEW: packed-FP32 math. h and W held as float2 pairs; the 10-deep dot is
// 5 v_pk_fma_f32 + 1 horizontal add (gfx950 full-rate packed fp32), cutting
// per-step VALU issue ~40% (the scan is issue-bound: PF=8 already covered
// latency). xi is read from the padded layout as dwordx4+dword (2 vm instrs
// per step, so PF=16 keeps 32 loads in flight, under the vmcnt cap).
// 8 blocks x 64 threads: one wave per CU.
// ---------------------------------------------------------------------------
__global__ __launch_bounds__(64) void scan_kernel(
    const float* __restrict__ xi, const float* __restrict__ Whh,
    float* __restrict__ out)
{
    const int gid  = blockIdx.x * 64 + threadIdx.x;    // 0..511
    const int b    = gid >> 1;
    const int half = gid & 1;
    const int j0   = half * 5;

    // Wp[jj][p] = ( W[j0+jj][perm(2p)], W[j0+jj][perm(2p+1)] ),
    // perm(k) = k<5 ? k+j0 : k-j0  (own dims first, matching h layout)
    f2 Wp[5][5];
#pragma unroll
    for (int jj = 0; jj < 5; ++jj)
#pragma unroll
        for (int p = 0; p < 5; ++p) {
            const int k0 = 2 * p, k1 = 2 * p + 1;
            const int c0 = (k0 < 5) ? (k0 + j0) : (k0 - j0);
            const int c1 = (k1 < 5) ? (k1 + j0) : (k1 - j0);
            Wp[jj][p] = mk2(Whh[(j0 + jj) * HID + c0],
                            Whh[(j0 + jj) * HID + c1]);
        }

    f2 H[5];
#pragma unroll
    for (int p = 0; p < 5; ++p) H[p] = mk2(0.f, 0.f);

    const float* xib  = xi  + b * XIP + half * 8;   // 32B-aligned
    float*       outb = out + b * HID + j0;

    // fill the ring: steps 0..PF-1
    float buf[PF][5];
#pragma unroll
    for (int i = 0; i < PF; ++i) {
        const float* p = xib + (long)i * (BATCH * XIP);
        const f4 v = *(const f4*)p;
        buf[i][0] = v[0]; buf[i][1] = v[1]; buf[i][2] = v[2]; buf[i][3] = v[3];
        buf[i][4] = p[4];
    }

    for (int t0 = 0; t0 < SEQ - PF; t0 += PF) {
#pragma unroll
        for (int i = 0; i < PF; ++i) {
            const int t = t0 + i;

            float cur[5];
#pragma unroll
            for (int jj = 0; jj < 5; ++jj) cur[jj] = buf[i][jj];

            // issue prefetch for t+PF immediately (full window)
            {
                const float* p = xib + (long)(t + PF) * (BATCH * XIP);
                const f4 v = *(const f4*)p;
                buf[i][0] = v[0]; buf[i][1] = v[1];
                buf[i][2] = v[2]; buf[i][3] = v[3];
                buf[i][4] = p[4];
            }

            float s[5];
#pragma unroll
            for (int jj = 0; jj < 5; ++jj) {
                f2 a = mk2(cur[jj], 0.f);
#pragma unroll
                for (int q = 0; q < 5; ++q)
                    a = __builtin_elementwise_fma(Wp[jj][q], H[q], a);
                s[jj] = fmaxf(a[0] + a[1], 0.f);
            }

            float* po = outb + (long)t * (BATCH * HID);
#pragma unroll
            for (int jj = 0; jj < 5; ++jj) po[jj] = s[jj];

            float shf[5];
#pragma unroll
            for (int jj = 0; jj < 5; ++jj) shf[jj] = __shfl_xor(s[jj], 1, 64);
            H[0] = mk2(s[0],   s[1]);
            H[1] = mk2(s[2],   s[3]);
            H[2] = mk2(s[4],   shf[0]);
            H[3] = mk2(shf[1], shf[2]);
            H[4] = mk2(shf[3], shf[4]);
        }
    }

    // tail: last PF steps, ring already holds them, no prefetch
#pragma unroll
    for (int i = 0; i < PF; ++i) {
        const int t = SEQ - PF + i;

        float s[5];
#pragma unroll
        for (int jj = 0; jj < 5; ++jj) {
            f2 a = mk2(buf[i][jj], 0.f);
#pragma unroll
            for (int q = 0; q < 5; ++q)
                a = __builtin_elementwise_fma(Wp[jj][q], H[q], a);
            s[jj] = fmaxf(a[0] + a[1], 0.f);
        }

        float* po = outb + (long)t * (BATCH * HID);
#pragma unroll
        for (int jj = 0; jj < 5; ++jj) po[jj] = s[jj];

        float shf[5];
#pragma unroll
        for (int jj = 0; jj < 5; ++jj) shf[jj] = __shfl_xor(s[jj], 1, 64);
        H[0] = mk2(s[0],   s[1]);
        H[1] = mk2(s[2],   s[3]);
        H[2] = mk2(s[4],   shf[0]);
        H[3] = mk2(shf[1], shf[2]);
        H[4] = mk2(shf[3], shf[4]);
    }

    // h_n: this thread owns dims j0..j0+4 = h[0..4] = H[0..2] lo halves
    float* pl = out + (long)SEQ * BATCH * HID + b * HID + j0;
    pl[0] = H[0][0]; pl[1] = H[0][1]; pl[2] = H[1][0];
    pl[3] = H[1][1]; pl[4] = H[2][0];
}

// ---------------------------------------------------------------------------
extern "C" void kernel_launch(void* const* d_in, const int* in_sizes, int n_in,
                              void* d_out, int out_size, void* d_ws, size_t ws_size,
                              hipStream_t stream)
{
    const float* x   = (const float*)d_in[0];
    const float* Wih = (const float*)d_in[1];
    const float* Whh = (const float*)d_in[2];
    const float* bih = (const float*)d_in[3];
    const float* bhh = (const float*)d_in[4];
    float* out = (float*)d_out;
    float* xi  = (float*)d_ws;   // SEQ*BATCH*XIP floats = 8.39 MB (padded)

    xproj_kernel<<<512, 256, 0, stream>>>(x, Wih, bih, bhh, xi);
    scan_kernel<<<8, 64, 0, stream>>>(xi, Whh, out);
}